// Round 7
// baseline (158.637 us; speedup 1.0000x reference)
//
#include <hip/hip_runtime.h>
#include <stdint.h>

typedef uint16_t u16;
typedef uint32_t u32;
typedef __attribute__((ext_vector_type(8))) _Float16 f16x8;
typedef __attribute__((ext_vector_type(4))) float f32x4;

#define NB 2
#define NT 2048
#define NC 1024
#define NH 16
#define ND 64
#define NM (NB*NT)   // 4096 rows of x
#define LOG2E 1.44269504088896340736f

__device__ __forceinline__ u16 f2h(float f) {
  _Float16 h = (_Float16)f;   // RNE
  return __builtin_bit_cast(u16, h);
}

// ---------------- f32 -> f16 convert, 4 elems/thread ----------------
__global__ __launch_bounds__(256) void cvt_kernel(const float* __restrict__ src,
                                                  u16* __restrict__ dst, int n4) {
  int i = blockIdx.x * 256 + threadIdx.x;
  if (i >= n4) return;
  float4 v = ((const float4*)src)[i];
  ushort4 o;
  o.x = f2h(v.x); o.y = f2h(v.y); o.z = f2h(v.z); o.w = f2h(v.w);
  ((ushort4*)dst)[i] = o;
}

// 4 weights -> one contiguous f16 region (Wq|Wk|Wv|Wproj)
__global__ __launch_bounds__(256) void cvtw_kernel(const float* __restrict__ w0,
                                                   const float* __restrict__ w1,
                                                   const float* __restrict__ w2,
                                                   const float* __restrict__ w3,
                                                   u16* __restrict__ dst) {
  int i = blockIdx.x * 256 + threadIdx.x;       // 0 .. 4*NC*NC/4
  int which = i >> 18;                          // NC*NC/4 = 262144
  const float* src = (which == 0) ? w0 : (which == 1) ? w1 : (which == 2) ? w2 : w3;
  int j = i & 262143;
  float4 v = ((const float4*)src)[j];
  ushort4 o;
  o.x = f2h(v.x); o.y = f2h(v.y); o.z = f2h(v.z); o.w = f2h(v.w);
  ((ushort4*)dst)[i] = o;
}

// ---------------- async global->LDS 16B ----------------
__device__ __forceinline__ void gload16(const void* g, void* l) {
  __builtin_amdgcn_global_load_lds(
      (const __attribute__((address_space(1))) void*)g,
      (__attribute__((address_space(3))) void*)l, 16, 0, 0);
}

// ---------------- GEMM, both operands k-major (C[m][n] = sum_k A[m][k]*B[n][k]) ---
// EPI 0: QKV epilogue, LDS re-tiled + coalesced 16B stores:
//        q/k -> [BH][T][D] f16 (q *= 0.125*log2e), v -> [BH][D][T] f16 (transposed)
// EPI 1: f32 row-major output
template<int EPI>
__global__ __launch_bounds__(256) void gemm_bt(const u16* __restrict__ A,
                                               const u16* __restrict__ Bw,
                                               int K, int N,
                                               u16* __restrict__ oq, u16* __restrict__ okk,
                                               u16* __restrict__ ovt,
                                               float* __restrict__ of) {
  __shared__ __align__(16) u16 SH[2*128*64];
  u16* Al = SH;
  u16* Bl = SH + 128*64;
  const int tid = threadIdx.x, lane = tid & 63, wid = tid >> 6;
  const int g = lane >> 4, qq = lane & 15;
  const int wm = wid >> 1, wn = wid & 1;
  const int m0 = blockIdx.y * 128, n0 = blockIdx.x * 128;
  const int srow = lane >> 3;          // row within an 8-row staging issue
  const int scol = (lane & 7) * 8;     // k-offset (elements) within row

  f32x4 acc[4][4] = {};

  for (int kt = 0; kt < K; kt += 64) {
    #pragma unroll
    for (int pp = 0; pp < 4; ++pp) {
      int r = wid*32 + pp*8;
      gload16(A  + (size_t)(m0 + r + srow)*K + kt + scol, &Al[r*64]);
      gload16(Bw + (size_t)(n0 + r + srow)*K + kt + scol, &Bl[r*64]);
    }
    __syncthreads();
    #pragma unroll
    for (int kk = 0; kk < 2; ++kk) {
      f16x8 af[4], bfr[4];
      #pragma unroll
      for (int mt = 0; mt < 4; ++mt)
        af[mt] = *(const f16x8*)&Al[(wm*64 + mt*16 + qq)*64 + kk*32 + 8*g];
      #pragma unroll
      for (int nt = 0; nt < 4; ++nt)
        bfr[nt] = *(const f16x8*)&Bl[(wn*64 + nt*16 + qq)*64 + kk*32 + 8*g];
      #pragma unroll
      for (int mt = 0; mt < 4; ++mt)
        #pragma unroll
        for (int nt = 0; nt < 4; ++nt)
          acc[mt][nt] = __builtin_amdgcn_mfma_f32_16x16x32_f16(af[mt], bfr[nt], acc[mt][nt], 0, 0, 0);
    }
    __syncthreads();    // also makes SH safe for epilogue reuse after last iter
  }

  if (EPI == 0) {
    // per-wave private 64x64 u16 region in SH (no barrier needed)
    u16* reg = SH + wid*4096;
    const int sel = n0 >> 10;                 // block-uniform: 0=q, 1=k, 2=v
    const int h = ((n0 & 1023) >> 6) + wn;    // this wave's head
    const int bq = m0 >> 11;                  // block-uniform batch (m-range never crosses)

    if (sel < 2) {
      // layout [mloc][d], phys_d = d ^ (g<<4)  (conflict-free writes)
      const float scale = (sel == 0) ? 0.125f*LOG2E : 1.0f;
      #pragma unroll
      for (int mt = 0; mt < 4; ++mt)
        #pragma unroll
        for (int r = 0; r < 4; ++r) {
          int mloc = mt*16 + g*4 + r;
          #pragma unroll
          for (int nt = 0; nt < 4; ++nt) {
            int d = nt*16 + qq;
            reg[mloc*64 + (d ^ (g << 4))] = f2h(acc[mt][nt][r] * scale);
          }
        }
      u16* dst = (sel == 0) ? oq : okk;
      const int slot = lane & 7;
      #pragma unroll
      for (int i = 0; i < 8; ++i) {
        int row = i*8 + (lane >> 3);
        int physslot = slot ^ (((row >> 2) & 3) << 1);
        f16x8 vvv = *(const f16x8*)&reg[row*64 + physslot*8];
        int m = m0 + wm*64 + row;
        int t = m & (NT-1);
        *(f16x8*)(dst + (((size_t)(bq*NH + h)*NT + t)*ND) + slot*8) = vvv;
      }
    } else {
      // v: layout [d][t-local], phys_col = mloc ^ ((d&7)<<3); r-paired u32 writes
      #pragma unroll
      for (int nt = 0; nt < 4; ++nt) {
        int d = nt*16 + qq;
        int f = (d & 7) << 3;
        #pragma unroll
        for (int mt = 0; mt < 4; ++mt)
          #pragma unroll
          for (int rp = 0; rp < 2; ++rp) {
            int r = rp*2;
            int mloc = mt*16 + g*4 + r;
            u32 pk = (u32)f2h(acc[mt][nt][r]) | ((u32)f2h(acc[mt][nt][r+1]) << 16);
            *(u32*)&reg[d*64 + (mloc ^ f)] = pk;
          }
      }
      const int slot = lane & 7;
      const int t0 = m0 + wm*64;
      #pragma unroll
      for (int i = 0; i < 8; ++i) {
        int d = i*8 + (lane >> 3);
        int physslot = slot ^ (d & 7);
        f16x8 vvv = *(const f16x8*)&reg[d*64 + physslot*8];
        int t = (t0 & (NT-1)) + slot*8;
        *(f16x8*)(ovt + ((size_t)(bq*NH + h)*ND + d)*NT + t) = vvv;
      }
    }
  } else {
    #pragma unroll
    for (int mt = 0; mt < 4; ++mt)
      #pragma unroll
      for (int r = 0; r < 4; ++r) {
        int m = m0 + wm*64 + mt*16 + g*4 + r;
        #pragma unroll
        for (int nt = 0; nt < 4; ++nt) {
          int n = n0 + wn*64 + nt*16 + qq;
          of[(size_t)m*N + n] = acc[mt][nt][r];
        }
      }
  }
}

// ---------------- flash attention, causal, swapped-QK^T, aligned co-residency -
// grid: x = qtile (32), y = B*H (32). linear id = qtile + 32*bh ->
//   co-CU blocks {id, id+256, id+512, id+768} share the SAME qtile (bh +8 apart)
//   -> identical lifetimes -> 4-way concurrency for the whole block duration.
// Softmax VALU diet: per-lane partial defer check (no shfl on common path);
//   row-sum via ones-MFMA on the idle matrix pipe (no adds/shfls, and l is
//   consistent with the f16 P used in PV); epilogue needs no broadcast.
__global__ __launch_bounds__(256) void attn_kernel(const u16* __restrict__ q,
                                                   const u16* __restrict__ k,
                                                   const u16* __restrict__ vt,
                                                   u16* __restrict__ y) {
  __shared__ __align__(16) u16 Kl[2][64*64];
  __shared__ __align__(16) u16 Vl[2][64*64];
  __shared__ __align__(16) u16 Pl[4*16*64];
  const int tid = threadIdx.x, lane = tid & 63, wid = tid >> 6;
  const int g = lane >> 4, qq = lane & 15;
  const int qtile = blockIdx.x;
  const int bh = blockIdx.y;
  const int qs = qtile * 64;
  const u16* qp = q  + (size_t)bh*NT*ND;
  const u16* kp = k  + (size_t)bh*NT*ND;
  const u16* vp = vt + (size_t)bh*ND*NT;
  const int b = bh >> 4, h = bh & 15;
  const int srow = lane >> 3;
  const int scol8 = (lane & 7) ^ (srow & 7);  // pre-swizzled 16B-slot in global source
  u16* pl = &Pl[wid*1024];
  u32* plw = (u32*)pl;

  // Q B-fragment in registers (col q = qs + wid*16 + qq)
  f16x8 aq[2];
  {
    int t = qs + wid*16 + qq;
    #pragma unroll
    for (int c = 0; c < 2; ++c)
      aq[c] = *(const f16x8*)(qp + (size_t)t*ND + c*32 + 8*g);
  }

  f16x8 vones;
  #pragma unroll
  for (int i = 0; i < 8; ++i) vones[i] = (_Float16)1.0f;

  f32x4 accO[4] = {};               // O[q-local = g*4+r][d = nt*16+qq]
  f32x4 accS = {};                  // row-sum l[q-local = g*4+r] (ones-MFMA)
  float m_run = -1e30f;             // per-lane, row q = qq (replicated across g)

  const int ntiles = qtile + 1;     // causal: kv tiles 0..qtile

  // prologue: stage kv tile 0 into buf 0
  #pragma unroll
  for (int pp = 0; pp < 2; ++pp) {
    int issue = wid*2 + pp;
    int row = issue*8 + srow;
    gload16(kp + (size_t)row*ND + scol8*8, &Kl[0][issue*512]);
    gload16(vp + (size_t)row*NT + scol8*8, &Vl[0][issue*512]);
  }

  for (int kt = 0; kt < ntiles; ++kt) {
    const int kvs = kt*64;
    const int cur = kt & 1;
    __syncthreads();                // stage(kt) drained (all waves); buf cur^1 free

    if (kt + 1 < ntiles) {          // issue next-tile stage; lands under compute(kt)
      const int kvs2 = kvs + 64;
      #pragma unroll
      for (int pp = 0; pp < 2; ++pp) {
        int issue = wid*2 + pp;
        int row = issue*8 + srow;
        gload16(kp + (size_t)(kvs2 + row)*ND + scol8*8, &Kl[cur^1][issue*512]);
        gload16(vp + (size_t)row*NT + kvs2 + scol8*8, &Vl[cur^1][issue*512]);
      }
    }

    // S^T = K Q^T: rows kv (from K as A), cols q (from Q as B)
    f32x4 sacc[4] = {};             // sacc[nt][r]: kv = kvs+nt*16+g*4+r, q = qs+wid*16+qq
    __builtin_amdgcn_s_setprio(1);
    #pragma unroll
    for (int c = 0; c < 2; ++c) {
      #pragma unroll
      for (int nt = 0; nt < 4; ++nt) {
        int row = nt*16 + qq;
        int col = (c*32 + 8*g) ^ ((row & 7) << 3);
        f16x8 kb = *(const f16x8*)&Kl[cur][row*64 + col];
        sacc[nt] = __builtin_amdgcn_mfma_f32_16x16x32_f16(kb, aq[c], sacc[nt], 0, 0, 0);
      }
    }
    __builtin_amdgcn_s_setprio(0);

    // causal mask (wave-uniform skip: only diagonal tiles mask)
    if (kvs + 63 > qs + wid*16) {
      int qg = qs + wid*16 + qq;
      #pragma unroll
      for (int nt = 0; nt < 4; ++nt)
        #pragma unroll
        for (int r = 0; r < 4; ++r)
          if (kvs + nt*16 + g*4 + r > qg) sacc[nt][r] = -1e30f;
    }

    // per-lane partial max over this lane's 16 S-values (tree)
    float m0a = fmaxf(fmaxf(sacc[0][0], sacc[0][1]), fmaxf(sacc[0][2], sacc[0][3]));
    float m1a = fmaxf(fmaxf(sacc[1][0], sacc[1][1]), fmaxf(sacc[1][2], sacc[1][3]));
    float m2a = fmaxf(fmaxf(sacc[2][0], sacc[2][1]), fmaxf(sacc[2][2], sacc[2][3]));
    float m3a = fmaxf(fmaxf(sacc[3][0], sacc[3][1]), fmaxf(sacc[3][2], sacc[3][3]));
    float mloc = fmaxf(fmaxf(m0a, m1a), fmaxf(m2a, m3a));

    // defer check on PARTIAL maxes: if every lane's partial is under the
    // threshold, the full row max is too -> no cross-lane reduce needed.
    const bool defer = __all(mloc <= m_run + 8.f);   // P bounded by 2^8, f16-safe
    float mnew;
    if (defer) {
      mnew = m_run;
    } else {
      float mf = fmaxf(mloc, __shfl_xor(mloc, 16));
      mf = fmaxf(mf, __shfl_xor(mf, 32));
      mnew = fmaxf(m_run, mf);
      float a = exp2f(m_run - mnew);
      m_run = mnew;
      #pragma unroll
      for (int r = 0; r < 4; ++r) {       // broadcast alpha[q=g*4+r] from lane (lane&48)+g*4+r
        float ar = __shfl(a, (lane & 48) + g*4 + r);
        #pragma unroll
        for (int nt = 0; nt < 4; ++nt) accO[nt][r] *= ar;
        accS[r] *= ar;
      }
    }

    // P = exp2(S - m); pack f16 pairs -> per-wave LDS [q][kv], 16B-slot swizzle
    #pragma unroll
    for (int nt = 0; nt < 4; ++nt) {
      float p0 = exp2f(sacc[nt][0] - mnew);
      float p1 = exp2f(sacc[nt][1] - mnew);
      float p2 = exp2f(sacc[nt][2] - mnew);
      float p3 = exp2f(sacc[nt][3] - mnew);
      u32 pk0 = __builtin_bit_cast(u32, __builtin_amdgcn_cvt_pkrtz(p0, p1));
      u32 pk1 = __builtin_bit_cast(u32, __builtin_amdgcn_cvt_pkrtz(p2, p3));
      int kv0 = nt*16 + g*4;
      plw[(qq*64 + (kv0 ^ ((qq & 7) << 3))) >> 1] = pk0;
      plw[(qq*64 + ((kv0 + 2) ^ ((qq & 7) << 3))) >> 1] = pk1;
    }

    // O += P V ; l += P·1 (row-sum on the matrix pipe, same layout as accO)
    __builtin_amdgcn_s_setprio(1);
    #pragma unroll
    for (int c = 0; c < 2; ++c) {
      f16x8 pa = *(const f16x8*)&pl[qq*64 + ((c*32 + 8*g) ^ ((qq & 7) << 3))];
      accS = __builtin_amdgcn_mfma_f32_16x16x32_f16(pa, vones, accS, 0, 0, 0);
      #pragma unroll
      for (int nt = 0; nt < 4; ++nt) {
        int vrow = nt*16 + qq;
        int vcol = (c*32 + 8*g) ^ ((vrow & 7) << 3);
        f16x8 vb = *(const f16x8*)&Vl[cur][vrow*64 + vcol];
        accO[nt] = __builtin_amdgcn_mfma_f32_16x16x32_f16(pa, vb, accO[nt], 0, 0, 0);
      }
    }
    __builtin_amdgcn_s_setprio(0);
  }

  // epilogue: y[b][t][h*64+d] = O / l, f16 (l already in accO's layout)
  #pragma unroll
  for (int r = 0; r < 4; ++r) {
    float invr = 1.0f / accS[r];
    int t = qs + wid*16 + g*4 + r;
    #pragma unroll
    for (int nt = 0; nt < 4; ++nt) {
      int d = nt*16 + qq;
      y[((size_t)(b*NT + t))*NC + h*ND + d] = f2h(accO[nt][r] * invr);
    }
  }
}

// ---------------- launch ----------------
extern "C" void kernel_launch(void* const* d_in, const int* in_sizes, int n_in,
                              void* d_out, int out_size, void* d_ws, size_t ws_size,
                              hipStream_t stream) {
  const float* x  = (const float*)d_in[0];
  const float* Wq = (const float*)d_in[1];
  const float* Wk = (const float*)d_in[2];
  const float* Wv = (const float*)d_in[3];
  const float* Wp = (const float*)d_in[4];

  u16* xb   = (u16*)d_ws;                       // [4096][1024]
  u16* wqkv = xb   + (size_t)NM*NC;             // [3072][1024] (Wq|Wk|Wv rows)
  u16* wpj  = wqkv + (size_t)3*NC*NC;           // [1024][1024] (contiguous after wqkv)
  u16* qb   = wpj  + (size_t)NC*NC;             // [BH][T][D], pre-scaled log2e/8
  u16* kb   = qb   + (size_t)NM*NC;             // [BH][T][D]
  u16* vtb  = kb   + (size_t)NM*NC;             // [BH][D][T]
  u16* yb   = vtb  + (size_t)NM*NC;             // [4096][1024]
  size_t need = ((size_t)NM*NC*5 + (size_t)4*NC*NC) * sizeof(u16);
  if (ws_size < need) return;                   // fail loudly (output stays zero)

  cvt_kernel<<<NM*NC/4/256, 256, 0, stream>>>(x, xb, NM*NC/4);
  cvtw_kernel<<<4*NC*NC/4/256, 256, 0, stream>>>(Wq, Wk, Wv, Wp, wqkv);

  gemm_bt<0><<<dim3(3*NC/128, NM/128), 256, 0, stream>>>(xb, wqkv, NC, 3*NC,
                                                         qb, kb, vtb, nullptr);
  attn_kernel<<<dim3(32, NB*NH), 256, 0, stream>>>(qb, kb, vtb, yb);
  gemm_bt<1><<<dim3(NC/128, NM/128), 256, 0, stream>>>(yb, wpj, NC, NC,
                                                       nullptr, nullptr, nullptr,
                                                       (float*)d_out);
}

// Round 8
// 134.561 us; speedup vs baseline: 1.1789x; 1.1789x over previous
//
#include <hip/hip_runtime.h>
#include <stdint.h>

typedef uint16_t u16;
typedef uint32_t u32;
typedef __attribute__((ext_vector_type(8))) _Float16 f16x8;
typedef __attribute__((ext_vector_type(4))) float f32x4;

#define NB 2
#define NT 2048
#define NC 1024
#define NH 16
#define ND 64
#define NM (NB*NT)   // 4096 rows of x
#define LOG2E 1.44269504088896340736f

__device__ __forceinline__ u16 f2h(float f) {
  _Float16 h = (_Float16)f;   // RNE
  return __builtin_bit_cast(u16, h);
}

// ---------------- f32 -> f16 convert, 4 elems/thread ----------------
__global__ __launch_bounds__(256) void cvt_kernel(const float* __restrict__ src,
                                                  u16* __restrict__ dst, int n4) {
  int i = blockIdx.x * 256 + threadIdx.x;
  if (i >= n4) return;
  float4 v = ((const float4*)src)[i];
  ushort4 o;
  o.x = f2h(v.x); o.y = f2h(v.y); o.z = f2h(v.z); o.w = f2h(v.w);
  ((ushort4*)dst)[i] = o;
}

// 4 weights -> one contiguous f16 region (Wq|Wk|Wv|Wproj)
__global__ __launch_bounds__(256) void cvtw_kernel(const float* __restrict__ w0,
                                                   const float* __restrict__ w1,
                                                   const float* __restrict__ w2,
                                                   const float* __restrict__ w3,
                                                   u16* __restrict__ dst) {
  int i = blockIdx.x * 256 + threadIdx.x;       // 0 .. 4*NC*NC/4
  int which = i >> 18;                          // NC*NC/4 = 262144
  const float* src = (which == 0) ? w0 : (which == 1) ? w1 : (which == 2) ? w2 : w3;
  int j = i & 262143;
  float4 v = ((const float4*)src)[j];
  ushort4 o;
  o.x = f2h(v.x); o.y = f2h(v.y); o.z = f2h(v.z); o.w = f2h(v.w);
  ((ushort4*)dst)[i] = o;
}

// ---------------- async global->LDS 16B ----------------
__device__ __forceinline__ void gload16(const void* g, void* l) {
  __builtin_amdgcn_global_load_lds(
      (const __attribute__((address_space(1))) void*)g,
      (__attribute__((address_space(3))) void*)l, 16, 0, 0);
}

// ---------------- GEMM, both operands k-major (C[m][n] = sum_k A[m][k]*B[n][k]) ---
// EPI 0: QKV epilogue, LDS re-tiled + coalesced 16B stores:
//        q/k -> [BH][T][D] f16 (q *= 0.125*log2e), v -> [BH][D][T] f16 (transposed)
// EPI 1: f32 row-major output
template<int EPI>
__global__ __launch_bounds__(256) void gemm_bt(const u16* __restrict__ A,
                                               const u16* __restrict__ Bw,
                                               int K, int N,
                                               u16* __restrict__ oq, u16* __restrict__ okk,
                                               u16* __restrict__ ovt,
                                               float* __restrict__ of) {
  __shared__ __align__(16) u16 SH[2*128*64];
  u16* Al = SH;
  u16* Bl = SH + 128*64;
  const int tid = threadIdx.x, lane = tid & 63, wid = tid >> 6;
  const int g = lane >> 4, qq = lane & 15;
  const int wm = wid >> 1, wn = wid & 1;
  const int m0 = blockIdx.y * 128, n0 = blockIdx.x * 128;
  const int srow = lane >> 3;          // row within an 8-row staging issue
  const int scol = (lane & 7) * 8;     // k-offset (elements) within row

  f32x4 acc[4][4] = {};

  for (int kt = 0; kt < K; kt += 64) {
    #pragma unroll
    for (int pp = 0; pp < 4; ++pp) {
      int r = wid*32 + pp*8;
      gload16(A  + (size_t)(m0 + r + srow)*K + kt + scol, &Al[r*64]);
      gload16(Bw + (size_t)(n0 + r + srow)*K + kt + scol, &Bl[r*64]);
    }
    __syncthreads();
    #pragma unroll
    for (int kk = 0; kk < 2; ++kk) {
      f16x8 af[4], bfr[4];
      #pragma unroll
      for (int mt = 0; mt < 4; ++mt)
        af[mt] = *(const f16x8*)&Al[(wm*64 + mt*16 + qq)*64 + kk*32 + 8*g];
      #pragma unroll
      for (int nt = 0; nt < 4; ++nt)
        bfr[nt] = *(const f16x8*)&Bl[(wn*64 + nt*16 + qq)*64 + kk*32 + 8*g];
      #pragma unroll
      for (int mt = 0; mt < 4; ++mt)
        #pragma unroll
        for (int nt = 0; nt < 4; ++nt)
          acc[mt][nt] = __builtin_amdgcn_mfma_f32_16x16x32_f16(af[mt], bfr[nt], acc[mt][nt], 0, 0, 0);
    }
    __syncthreads();    // also makes SH safe for epilogue reuse after last iter
  }

  if (EPI == 0) {
    // per-wave private 64x64 u16 region in SH (no barrier needed)
    u16* reg = SH + wid*4096;
    const int sel = n0 >> 10;                 // block-uniform: 0=q, 1=k, 2=v
    const int h = ((n0 & 1023) >> 6) + wn;    // this wave's head
    const int bq = m0 >> 11;                  // block-uniform batch (m-range never crosses)

    if (sel < 2) {
      // layout [mloc][d], phys_d = d ^ (g<<4)  (conflict-free writes)
      const float scale = (sel == 0) ? 0.125f*LOG2E : 1.0f;
      #pragma unroll
      for (int mt = 0; mt < 4; ++mt)
        #pragma unroll
        for (int r = 0; r < 4; ++r) {
          int mloc = mt*16 + g*4 + r;
          #pragma unroll
          for (int nt = 0; nt < 4; ++nt) {
            int d = nt*16 + qq;
            reg[mloc*64 + (d ^ (g << 4))] = f2h(acc[mt][nt][r] * scale);
          }
        }
      u16* dst = (sel == 0) ? oq : okk;
      const int slot = lane & 7;
      #pragma unroll
      for (int i = 0; i < 8; ++i) {
        int row = i*8 + (lane >> 3);
        int physslot = slot ^ (((row >> 2) & 3) << 1);
        f16x8 vvv = *(const f16x8*)&reg[row*64 + physslot*8];
        int m = m0 + wm*64 + row;
        int t = m & (NT-1);
        *(f16x8*)(dst + (((size_t)(bq*NH + h)*NT + t)*ND) + slot*8) = vvv;
      }
    } else {
      // v: layout [d][t-local], phys_col = mloc ^ ((d&7)<<3); r-paired u32 writes
      #pragma unroll
      for (int nt = 0; nt < 4; ++nt) {
        int d = nt*16 + qq;
        int f = (d & 7) << 3;
        #pragma unroll
        for (int mt = 0; mt < 4; ++mt)
          #pragma unroll
          for (int rp = 0; rp < 2; ++rp) {
            int r = rp*2;
            int mloc = mt*16 + g*4 + r;
            u32 pk = (u32)f2h(acc[mt][nt][r]) | ((u32)f2h(acc[mt][nt][r+1]) << 16);
            *(u32*)&reg[d*64 + (mloc ^ f)] = pk;
          }
      }
      const int slot = lane & 7;
      const int t0 = m0 + wm*64;
      #pragma unroll
      for (int i = 0; i < 8; ++i) {
        int d = i*8 + (lane >> 3);
        int physslot = slot ^ (d & 7);
        f16x8 vvv = *(const f16x8*)&reg[d*64 + physslot*8];
        int t = (t0 & (NT-1)) + slot*8;
        *(f16x8*)(ovt + ((size_t)(bq*NH + h)*ND + d)*NT + t) = vvv;
      }
    }
  } else {
    #pragma unroll
    for (int mt = 0; mt < 4; ++mt)
      #pragma unroll
      for (int r = 0; r < 4; ++r) {
        int m = m0 + wm*64 + mt*16 + g*4 + r;
        #pragma unroll
        for (int nt = 0; nt < 4; ++nt) {
          int n = n0 + wn*64 + nt*16 + qq;
          of[(size_t)m*N + n] = acc[mt][nt][r];
        }
      }
  }
}

// ---------------- flash attention: R4 grid (proven balance) + R6 VALU diet ----
// grid: x = B*H (32), y = 32 -> qtile = y ^ h[y>>3], h={0,31,8,23}.
//   Co-CU blocks (id stride 256 -> y +8) get qtiles {a,23-a,24+a,15-a}
//   -> EXACTLY 66 kv-iters per CU (cross-CU balance, the thing R6 broke).
//   XCD = id%8 = bh%8 -> 4 bh per XCD -> K/V (2MB) resident in 4MB XCD L2.
// VALU diet: per-lane partial defer check (zero cross-lane ops on common path);
//   row-sum l via ones-MFMA on the matrix pipe, same layout as accO.
__global__ __launch_bounds__(256) void attn_kernel(const u16* __restrict__ q,
                                                   const u16* __restrict__ k,
                                                   const u16* __restrict__ vt,
                                                   u16* __restrict__ y) {
  __shared__ __align__(16) u16 Kl[2][64*64];
  __shared__ __align__(16) u16 Vl[2][64*64];
  __shared__ __align__(16) u16 Pl[4*16*64];
  const int tid = threadIdx.x, lane = tid & 63, wid = tid >> 6;
  const int g = lane >> 4, qq = lane & 15;
  const int bh = blockIdx.x;
  const int yy = blockIdx.y;
  const int hmap4[4] = {0, 31, 8, 23};
  const int qtile = yy ^ hmap4[yy >> 3];
  const int qs = qtile * 64;
  const u16* qp = q  + (size_t)bh*NT*ND;
  const u16* kp = k  + (size_t)bh*NT*ND;
  const u16* vp = vt + (size_t)bh*ND*NT;
  const int b = bh >> 4, h = bh & 15;
  const int srow = lane >> 3;
  const int scol8 = (lane & 7) ^ (srow & 7);  // pre-swizzled 16B-slot in global source
  u16* pl = &Pl[wid*1024];
  u32* plw = (u32*)pl;

  // Q B-fragment in registers (col q = qs + wid*16 + qq)
  f16x8 aq[2];
  {
    int t = qs + wid*16 + qq;
    #pragma unroll
    for (int c = 0; c < 2; ++c)
      aq[c] = *(const f16x8*)(qp + (size_t)t*ND + c*32 + 8*g);
  }

  f16x8 vones;
  #pragma unroll
  for (int i = 0; i < 8; ++i) vones[i] = (_Float16)1.0f;

  f32x4 accO[4] = {};               // O[q-local = g*4+r][d = nt*16+qq]
  f32x4 accS = {};                  // row-sum l[q-local = g*4+r] (ones-MFMA)
  float m_run = -1e30f;             // per-lane, row q = qq (replicated across g)

  const int ntiles = qtile + 1;     // causal: kv tiles 0..qtile

  // prologue: stage kv tile 0 into buf 0
  #pragma unroll
  for (int pp = 0; pp < 2; ++pp) {
    int issue = wid*2 + pp;
    int row = issue*8 + srow;
    gload16(kp + (size_t)row*ND + scol8*8, &Kl[0][issue*512]);
    gload16(vp + (size_t)row*NT + scol8*8, &Vl[0][issue*512]);
  }

  for (int kt = 0; kt < ntiles; ++kt) {
    const int kvs = kt*64;
    const int cur = kt & 1;
    __syncthreads();                // stage(kt) drained (all waves); buf cur^1 free

    if (kt + 1 < ntiles) {          // issue next-tile stage; lands under compute(kt)
      const int kvs2 = kvs + 64;
      #pragma unroll
      for (int pp = 0; pp < 2; ++pp) {
        int issue = wid*2 + pp;
        int row = issue*8 + srow;
        gload16(kp + (size_t)(kvs2 + row)*ND + scol8*8, &Kl[cur^1][issue*512]);
        gload16(vp + (size_t)row*NT + kvs2 + scol8*8, &Vl[cur^1][issue*512]);
      }
    }

    // S^T = K Q^T: rows kv (from K as A), cols q (from Q as B)
    f32x4 sacc[4] = {};             // sacc[nt][r]: kv = kvs+nt*16+g*4+r, q = qs+wid*16+qq
    __builtin_amdgcn_s_setprio(1);
    #pragma unroll
    for (int c = 0; c < 2; ++c) {
      #pragma unroll
      for (int nt = 0; nt < 4; ++nt) {
        int row = nt*16 + qq;
        int col = (c*32 + 8*g) ^ ((row & 7) << 3);
        f16x8 kb = *(const f16x8*)&Kl[cur][row*64 + col];
        sacc[nt] = __builtin_amdgcn_mfma_f32_16x16x32_f16(kb, aq[c], sacc[nt], 0, 0, 0);
      }
    }
    __builtin_amdgcn_s_setprio(0);

    // causal mask (wave-uniform skip: only diagonal tiles mask)
    if (kvs + 63 > qs + wid*16) {
      int qg = qs + wid*16 + qq;
      #pragma unroll
      for (int nt = 0; nt < 4; ++nt)
        #pragma unroll
        for (int r = 0; r < 4; ++r)
          if (kvs + nt*16 + g*4 + r > qg) sacc[nt][r] = -1e30f;
    }

    // per-lane partial max over this lane's 16 S-values (tree)
    float m0a = fmaxf(fmaxf(sacc[0][0], sacc[0][1]), fmaxf(sacc[0][2], sacc[0][3]));
    float m1a = fmaxf(fmaxf(sacc[1][0], sacc[1][1]), fmaxf(sacc[1][2], sacc[1][3]));
    float m2a = fmaxf(fmaxf(sacc[2][0], sacc[2][1]), fmaxf(sacc[2][2], sacc[2][3]));
    float m3a = fmaxf(fmaxf(sacc[3][0], sacc[3][1]), fmaxf(sacc[3][2], sacc[3][3]));
    float mloc = fmaxf(fmaxf(m0a, m1a), fmaxf(m2a, m3a));

    // defer check on PARTIAL maxes: if every lane's partial is under the
    // threshold, the full row max is too -> no cross-lane reduce needed.
    const bool defer = __all(mloc <= m_run + 8.f);   // P bounded by 2^8, f16-safe
    float mnew;
    if (defer) {
      mnew = m_run;
    } else {
      float mf = fmaxf(mloc, __shfl_xor(mloc, 16));
      mf = fmaxf(mf, __shfl_xor(mf, 32));
      mnew = fmaxf(m_run, mf);
      float a = exp2f(m_run - mnew);
      m_run = mnew;
      #pragma unroll
      for (int r = 0; r < 4; ++r) {       // broadcast alpha[q=g*4+r] from lane (lane&48)+g*4+r
        float ar = __shfl(a, (lane & 48) + g*4 + r);
        #pragma unroll
        for (int nt = 0; nt < 4; ++nt) accO[nt][r] *= ar;
        accS[r] *= ar;
      }
    }

    // P = exp2(S - m); pack f16 pairs -> per-wave LDS [q][kv], 16B-slot swizzle
    #pragma unroll
    for (int nt = 0; nt < 4; ++nt) {
      float p0 = exp2f(sacc[nt][0] - mnew);
      float p1 = exp2f(sacc[nt][1] - mnew);
      float p2 = exp2f(sacc[nt][2] - mnew);
      float p3 = exp2f(sacc[nt][3] - mnew);
      u32 pk0 = __builtin_bit_cast(u32, __builtin_amdgcn_cvt_pkrtz(p0, p1));
      u32 pk1 = __builtin_bit_cast(u32, __builtin_amdgcn_cvt_pkrtz(p2, p3));
      int kv0 = nt*16 + g*4;
      plw[(qq*64 + (kv0 ^ ((qq & 7) << 3))) >> 1] = pk0;
      plw[(qq*64 + ((kv0 + 2) ^ ((qq & 7) << 3))) >> 1] = pk1;
    }

    // O += P V ; l += P·1 (row-sum on the matrix pipe, same layout as accO)
    __builtin_amdgcn_s_setprio(1);
    #pragma unroll
    for (int c = 0; c < 2; ++c) {
      f16x8 pa = *(const f16x8*)&pl[qq*64 + ((c*32 + 8*g) ^ ((qq & 7) << 3))];
      accS = __builtin_amdgcn_mfma_f32_16x16x32_f16(pa, vones, accS, 0, 0, 0);
      #pragma unroll
      for (int nt = 0; nt < 4; ++nt) {
        int vrow = nt*16 + qq;
        int vcol = (c*32 + 8*g) ^ ((vrow & 7) << 3);
        f16x8 vb = *(const f16x8*)&Vl[cur][vrow*64 + vcol];
        accO[nt] = __builtin_amdgcn_mfma_f32_16x16x32_f16(pa, vb, accO[nt], 0, 0, 0);
      }
    }
    __builtin_amdgcn_s_setprio(0);
  }

  // epilogue: y[b][t][h*64+d] = O / l, f16 (l already in accO's layout)
  #pragma unroll
  for (int r = 0; r < 4; ++r) {
    float invr = 1.0f / accS[r];
    int t = qs + wid*16 + g*4 + r;
    #pragma unroll
    for (int nt = 0; nt < 4; ++nt) {
      int d = nt*16 + qq;
      y[((size_t)(b*NT + t))*NC + h*ND + d] = f2h(accO[nt][r] * invr);
    }
  }
}

// ---------------- launch ----------------
extern "C" void kernel_launch(void* const* d_in, const int* in_sizes, int n_in,
                              void* d_out, int out_size, void* d_ws, size_t ws_size,
                              hipStream_t stream) {
  const float* x  = (const float*)d_in[0];
  const float* Wq = (const float*)d_in[1];
  const float* Wk = (const float*)d_in[2];
  const float* Wv = (const float*)d_in[3];
  const float* Wp = (const float*)d_in[4];

  u16* xb   = (u16*)d_ws;                       // [4096][1024]
  u16* wqkv = xb   + (size_t)NM*NC;             // [3072][1024] (Wq|Wk|Wv rows)
  u16* wpj  = wqkv + (size_t)3*NC*NC;           // [1024][1024] (contiguous after wqkv)
  u16* qb   = wpj  + (size_t)NC*NC;             // [BH][T][D], pre-scaled log2e/8
  u16* kb   = qb   + (size_t)NM*NC;             // [BH][T][D]
  u16* vtb  = kb   + (size_t)NM*NC;             // [BH][D][T]
  u16* yb   = vtb  + (size_t)NM*NC;             // [4096][1024]
  size_t need = ((size_t)NM*NC*5 + (size_t)4*NC*NC) * sizeof(u16);
  if (ws_size < need) return;                   // fail loudly (output stays zero)

  cvt_kernel<<<NM*NC/4/256, 256, 0, stream>>>(x, xb, NM*NC/4);
  cvtw_kernel<<<4*NC*NC/4/256, 256, 0, stream>>>(Wq, Wk, Wv, Wp, wqkv);

  gemm_bt<0><<<dim3(3*NC/128, NM/128), 256, 0, stream>>>(xb, wqkv, NC, 3*NC,
                                                         qb, kb, vtb, nullptr);
  attn_kernel<<<dim3(NB*NH, 32), 256, 0, stream>>>(qb, kb, vtb, yb);
  gemm_bt<1><<<dim3(NC/128, NM/128), 256, 0, stream>>>(yb, wpj, NC, NC,
                                                       nullptr, nullptr, nullptr,
                                                       (float*)d_out);
}

// Round 9
// 115.801 us; speedup vs baseline: 1.3699x; 1.1620x over previous
//
#include <hip/hip_runtime.h>
#include <stdint.h>

typedef uint16_t u16;
typedef uint32_t u32;
typedef __attribute__((ext_vector_type(8))) _Float16 f16x8;
typedef __attribute__((ext_vector_type(4))) float f32x4;

#define NB 2
#define NT 2048
#define NC 1024
#define NH 16
#define ND 64
#define NM (NB*NT)   // 4096 rows of x
#define LOG2E 1.44269504088896340736f

__device__ __forceinline__ u16 f2h(float f) {
  _Float16 h = (_Float16)f;   // RNE
  return __builtin_bit_cast(u16, h);
}

// ---------------- f32 -> f16 convert, 4 elems/thread ----------------
__global__ __launch_bounds__(256) void cvt_kernel(const float* __restrict__ src,
                                                  u16* __restrict__ dst, int n4) {
  int i = blockIdx.x * 256 + threadIdx.x;
  if (i >= n4) return;
  float4 v = ((const float4*)src)[i];
  ushort4 o;
  o.x = f2h(v.x); o.y = f2h(v.y); o.z = f2h(v.z); o.w = f2h(v.w);
  ((ushort4*)dst)[i] = o;
}

// 4 weights -> one contiguous f16 region (Wq|Wk|Wv|Wproj)
__global__ __launch_bounds__(256) void cvtw_kernel(const float* __restrict__ w0,
                                                   const float* __restrict__ w1,
                                                   const float* __restrict__ w2,
                                                   const float* __restrict__ w3,
                                                   u16* __restrict__ dst) {
  int i = blockIdx.x * 256 + threadIdx.x;       // 0 .. 4*NC*NC/4
  int which = i >> 18;                          // NC*NC/4 = 262144
  const float* src = (which == 0) ? w0 : (which == 1) ? w1 : (which == 2) ? w2 : w3;
  int j = i & 262143;
  float4 v = ((const float4*)src)[j];
  ushort4 o;
  o.x = f2h(v.x); o.y = f2h(v.y); o.z = f2h(v.z); o.w = f2h(v.w);
  ((ushort4*)dst)[i] = o;
}

// ---------------- async global->LDS 16B ----------------
__device__ __forceinline__ void gload16(const void* g, void* l) {
  __builtin_amdgcn_global_load_lds(
      (const __attribute__((address_space(1))) void*)g,
      (__attribute__((address_space(3))) void*)l, 16, 0, 0);
}

// ---------------- GEMM, both operands k-major (C[m][n] = sum_k A[m][k]*B[n][k]) ---
// Double-buffered staging (stage kt+1 under compute kt, one barrier/iter) +
// XOR-swizzled LDS (pre-swizzled global source slot, swizzled ds_read slot)
// -> conflict-free ds_read_b128.
// EPI 0: QKV epilogue, LDS re-tiled + coalesced 16B stores:
//        q/k -> [BH][T][D] f16 (q *= 0.125*log2e), v -> [BH][D][T] f16 (transposed)
// EPI 1: f32 row-major output
template<int EPI>
__global__ __launch_bounds__(256) void gemm_bt(const u16* __restrict__ A,
                                               const u16* __restrict__ Bw,
                                               int K, int N,
                                               u16* __restrict__ oq, u16* __restrict__ okk,
                                               u16* __restrict__ ovt,
                                               float* __restrict__ of) {
  __shared__ __align__(16) u16 SH[4*128*64];   // 64 KB: A dbuf (32K) | B dbuf (32K)
  u16* Al = SH;                                // [2][128][64]
  u16* Bl = SH + 2*128*64;                     // [2][128][64]
  const int tid = threadIdx.x, lane = tid & 63, wid = tid >> 6;
  const int g = lane >> 4, qq = lane & 15;
  const int wm = wid >> 1, wn = wid & 1;
  const int m0 = blockIdx.y * 128, n0 = blockIdx.x * 128;
  const int srow = lane >> 3;            // row within an 8-row staging issue (0..7)
  const int scol8 = (lane & 7) ^ srow;   // pre-swizzled 16B-slot in global source
  // LDS[row][slot] = global[row][slot ^ (row&7)]  (dest linear, source swizzled)

  f32x4 acc[4][4] = {};
  const int nk = K >> 6;

  // prologue: stage K-tile 0 into buf 0
  #pragma unroll
  for (int pp = 0; pp < 4; ++pp) {
    int r = wid*32 + pp*8;
    gload16(A  + (size_t)(m0 + r + srow)*K + scol8*8, &Al[r*64]);
    gload16(Bw + (size_t)(n0 + r + srow)*K + scol8*8, &Bl[r*64]);
  }

  for (int kt = 0; kt < nk; ++kt) {
    const int cur = kt & 1;
    __syncthreads();              // stage(kt) drained; buf cur^1 reads all done
    if (kt + 1 < nk) {            // stage next tile; latency hides under compute
      const int k1 = (kt + 1) << 6;
      #pragma unroll
      for (int pp = 0; pp < 4; ++pp) {
        int r = wid*32 + pp*8;
        gload16(A  + (size_t)(m0 + r + srow)*K + k1 + scol8*8, &Al[(cur^1)*8192 + r*64]);
        gload16(Bw + (size_t)(n0 + r + srow)*K + k1 + scol8*8, &Bl[(cur^1)*8192 + r*64]);
      }
    }
    #pragma unroll
    for (int kk = 0; kk < 2; ++kk) {
      f16x8 af[4], bfr[4];
      #pragma unroll
      for (int mt = 0; mt < 4; ++mt) {
        int row = wm*64 + mt*16 + qq;
        af[mt] = *(const f16x8*)&Al[cur*8192 + row*64 + (((kk*4 + g) ^ (qq & 7))*8)];
      }
      #pragma unroll
      for (int nt = 0; nt < 4; ++nt) {
        int row = wn*64 + nt*16 + qq;
        bfr[nt] = *(const f16x8*)&Bl[cur*8192 + row*64 + (((kk*4 + g) ^ (qq & 7))*8)];
      }
      #pragma unroll
      for (int mt = 0; mt < 4; ++mt)
        #pragma unroll
        for (int nt = 0; nt < 4; ++nt)
          acc[mt][nt] = __builtin_amdgcn_mfma_f32_16x16x32_f16(af[mt], bfr[nt], acc[mt][nt], 0, 0, 0);
    }
  }

  if (EPI == 0) {
    __syncthreads();    // all waves done reading SH before epilogue reuse
    // per-wave private 64x64 u16 region in SH (no further barrier needed)
    u16* reg = SH + wid*4096;
    const int sel = n0 >> 10;                 // block-uniform: 0=q, 1=k, 2=v
    const int h = ((n0 & 1023) >> 6) + wn;    // this wave's head
    const int bq = m0 >> 11;                  // block-uniform batch (m-range never crosses)

    if (sel < 2) {
      // layout [mloc][d], phys_d = d ^ (g<<4)  (conflict-free writes)
      const float scale = (sel == 0) ? 0.125f*LOG2E : 1.0f;
      #pragma unroll
      for (int mt = 0; mt < 4; ++mt)
        #pragma unroll
        for (int r = 0; r < 4; ++r) {
          int mloc = mt*16 + g*4 + r;
          #pragma unroll
          for (int nt = 0; nt < 4; ++nt) {
            int d = nt*16 + qq;
            reg[mloc*64 + (d ^ (g << 4))] = f2h(acc[mt][nt][r] * scale);
          }
        }
      u16* dst = (sel == 0) ? oq : okk;
      const int slot = lane & 7;
      #pragma unroll
      for (int i = 0; i < 8; ++i) {
        int row = i*8 + (lane >> 3);
        int physslot = slot ^ (((row >> 2) & 3) << 1);
        f16x8 vvv = *(const f16x8*)&reg[row*64 + physslot*8];
        int m = m0 + wm*64 + row;
        int t = m & (NT-1);
        *(f16x8*)(dst + (((size_t)(bq*NH + h)*NT + t)*ND) + slot*8) = vvv;
      }
    } else {
      // v: layout [d][t-local], phys_col = mloc ^ ((d&7)<<3); r-paired u32 writes
      #pragma unroll
      for (int nt = 0; nt < 4; ++nt) {
        int d = nt*16 + qq;
        int f = (d & 7) << 3;
        #pragma unroll
        for (int mt = 0; mt < 4; ++mt)
          #pragma unroll
          for (int rp = 0; rp < 2; ++rp) {
            int r = rp*2;
            int mloc = mt*16 + g*4 + r;
            u32 pk = (u32)f2h(acc[mt][nt][r]) | ((u32)f2h(acc[mt][nt][r+1]) << 16);
            *(u32*)&reg[d*64 + (mloc ^ f)] = pk;
          }
      }
      const int slot = lane & 7;
      const int t0 = m0 + wm*64;
      #pragma unroll
      for (int i = 0; i < 8; ++i) {
        int d = i*8 + (lane >> 3);
        int physslot = slot ^ (d & 7);
        f16x8 vvv = *(const f16x8*)&reg[d*64 + physslot*8];
        int t = (t0 & (NT-1)) + slot*8;
        *(f16x8*)(ovt + ((size_t)(bq*NH + h)*ND + d)*NT + t) = vvv;
      }
    }
  } else {
    #pragma unroll
    for (int mt = 0; mt < 4; ++mt)
      #pragma unroll
      for (int r = 0; r < 4; ++r) {
        int m = m0 + wm*64 + mt*16 + g*4 + r;
        #pragma unroll
        for (int nt = 0; nt < 4; ++nt) {
          int n = n0 + wn*64 + nt*16 + qq;
          of[(size_t)m*N + n] = acc[mt][nt][r];
        }
      }
  }
}

// ---------------- flash attention: R4 grid (proven balance) + R6 VALU diet ----
// grid: x = B*H (32), y = 32 -> qtile = y ^ h[y>>3], h={0,31,8,23}.
//   Co-CU blocks (id stride 256 -> y +8) get qtiles {a,23-a,24+a,15-a}
//   -> EXACTLY 66 kv-iters per CU. XCD = id%8 = bh%8 -> K/V L2-resident.
// VALU diet: per-lane partial defer check (zero cross-lane ops on common path);
//   row-sum l via ones-MFMA on the matrix pipe, same layout as accO.
__global__ __launch_bounds__(256) void attn_kernel(const u16* __restrict__ q,
                                                   const u16* __restrict__ k,
                                                   const u16* __restrict__ vt,
                                                   u16* __restrict__ y) {
  __shared__ __align__(16) u16 Kl[2][64*64];
  __shared__ __align__(16) u16 Vl[2][64*64];
  __shared__ __align__(16) u16 Pl[4*16*64];
  const int tid = threadIdx.x, lane = tid & 63, wid = tid >> 6;
  const int g = lane >> 4, qq = lane & 15;
  const int bh = blockIdx.x;
  const int yy = blockIdx.y;
  const int hmap4[4] = {0, 31, 8, 23};
  const int qtile = yy ^ hmap4[yy >> 3];
  const int qs = qtile * 64;
  const u16* qp = q  + (size_t)bh*NT*ND;
  const u16* kp = k  + (size_t)bh*NT*ND;
  const u16* vp = vt + (size_t)bh*ND*NT;
  const int b = bh >> 4, h = bh & 15;
  const int srow = lane >> 3;
  const int scol8 = (lane & 7) ^ (srow & 7);  // pre-swizzled 16B-slot in global source
  u16* pl = &Pl[wid*1024];
  u32* plw = (u32*)pl;

  // Q B-fragment in registers (col q = qs + wid*16 + qq)
  f16x8 aq[2];
  {
    int t = qs + wid*16 + qq;
    #pragma unroll
    for (int c = 0; c < 2; ++c)
      aq[c] = *(const f16x8*)(qp + (size_t)t*ND + c*32 + 8*g);
  }

  f16x8 vones;
  #pragma unroll
  for (int i = 0; i < 8; ++i) vones[i] = (_Float16)1.0f;

  f32x4 accO[4] = {};               // O[q-local = g*4+r][d = nt*16+qq]
  f32x4 accS = {};                  // row-sum l[q-local = g*4+r] (ones-MFMA)
  float m_run = -1e30f;             // per-lane, row q = qq (replicated across g)

  const int ntiles = qtile + 1;     // causal: kv tiles 0..qtile

  // prologue: stage kv tile 0 into buf 0
  #pragma unroll
  for (int pp = 0; pp < 2; ++pp) {
    int issue = wid*2 + pp;
    int row = issue*8 + srow;
    gload16(kp + (size_t)row*ND + scol8*8, &Kl[0][issue*512]);
    gload16(vp + (size_t)row*NT + scol8*8, &Vl[0][issue*512]);
  }

  for (int kt = 0; kt < ntiles; ++kt) {
    const int kvs = kt*64;
    const int cur = kt & 1;
    __syncthreads();                // stage(kt) drained (all waves); buf cur^1 free

    if (kt + 1 < ntiles) {          // issue next-tile stage; lands under compute(kt)
      const int kvs2 = kvs + 64;
      #pragma unroll
      for (int pp = 0; pp < 2; ++pp) {
        int issue = wid*2 + pp;
        int row = issue*8 + srow;
        gload16(kp + (size_t)(kvs2 + row)*ND + scol8*8, &Kl[cur^1][issue*512]);
        gload16(vp + (size_t)row*NT + kvs2 + scol8*8, &Vl[cur^1][issue*512]);
      }
    }

    // S^T = K Q^T: rows kv (from K as A), cols q (from Q as B)
    f32x4 sacc[4] = {};             // sacc[nt][r]: kv = kvs+nt*16+g*4+r, q = qs+wid*16+qq
    __builtin_amdgcn_s_setprio(1);
    #pragma unroll
    for (int c = 0; c < 2; ++c) {
      #pragma unroll
      for (int nt = 0; nt < 4; ++nt) {
        int row = nt*16 + qq;
        int col = (c*32 + 8*g) ^ ((row & 7) << 3);
        f16x8 kb = *(const f16x8*)&Kl[cur][row*64 + col];
        sacc[nt] = __builtin_amdgcn_mfma_f32_16x16x32_f16(kb, aq[c], sacc[nt], 0, 0, 0);
      }
    }
    __builtin_amdgcn_s_setprio(0);

    // causal mask (wave-uniform skip: only diagonal tiles mask)
    if (kvs + 63 > qs + wid*16) {
      int qg = qs + wid*16 + qq;
      #pragma unroll
      for (int nt = 0; nt < 4; ++nt)
        #pragma unroll
        for (int r = 0; r < 4; ++r)
          if (kvs + nt*16 + g*4 + r > qg) sacc[nt][r] = -1e30f;
    }

    // per-lane partial max over this lane's 16 S-values (tree)
    float m0a = fmaxf(fmaxf(sacc[0][0], sacc[0][1]), fmaxf(sacc[0][2], sacc[0][3]));
    float m1a = fmaxf(fmaxf(sacc[1][0], sacc[1][1]), fmaxf(sacc[1][2], sacc[1][3]));
    float m2a = fmaxf(fmaxf(sacc[2][0], sacc[2][1]), fmaxf(sacc[2][2], sacc[2][3]));
    float m3a = fmaxf(fmaxf(sacc[3][0], sacc[3][1]), fmaxf(sacc[3][2], sacc[3][3]));
    float mloc = fmaxf(fmaxf(m0a, m1a), fmaxf(m2a, m3a));

    // defer check on PARTIAL maxes: if every lane's partial is under the
    // threshold, the full row max is too -> no cross-lane reduce needed.
    const bool defer = __all(mloc <= m_run + 8.f);   // P bounded by 2^8, f16-safe
    float mnew;
    if (defer) {
      mnew = m_run;
    } else {
      float mf = fmaxf(mloc, __shfl_xor(mloc, 16));
      mf = fmaxf(mf, __shfl_xor(mf, 32));
      mnew = fmaxf(m_run, mf);
      float a = exp2f(m_run - mnew);
      m_run = mnew;
      #pragma unroll
      for (int r = 0; r < 4; ++r) {       // broadcast alpha[q=g*4+r] from lane (lane&48)+g*4+r
        float ar = __shfl(a, (lane & 48) + g*4 + r);
        #pragma unroll
        for (int nt = 0; nt < 4; ++nt) accO[nt][r] *= ar;
        accS[r] *= ar;
      }
    }

    // P = exp2(S - m); pack f16 pairs -> per-wave LDS [q][kv], 16B-slot swizzle
    #pragma unroll
    for (int nt = 0; nt < 4; ++nt) {
      float p0 = exp2f(sacc[nt][0] - mnew);
      float p1 = exp2f(sacc[nt][1] - mnew);
      float p2 = exp2f(sacc[nt][2] - mnew);
      float p3 = exp2f(sacc[nt][3] - mnew);
      u32 pk0 = __builtin_bit_cast(u32, __builtin_amdgcn_cvt_pkrtz(p0, p1));
      u32 pk1 = __builtin_bit_cast(u32, __builtin_amdgcn_cvt_pkrtz(p2, p3));
      int kv0 = nt*16 + g*4;
      plw[(qq*64 + (kv0 ^ ((qq & 7) << 3))) >> 1] = pk0;
      plw[(qq*64 + ((kv0 + 2) ^ ((qq & 7) << 3))) >> 1] = pk1;
    }

    // O += P V ; l += P·1 (row-sum on the matrix pipe, same layout as accO)
    __builtin_amdgcn_s_setprio(1);
    #pragma unroll
    for (int c = 0; c < 2; ++c) {
      f16x8 pa = *(const f16x8*)&pl[qq*64 + ((c*32 + 8*g) ^ ((qq & 7) << 3))];
      accS = __builtin_amdgcn_mfma_f32_16x16x32_f16(pa, vones, accS, 0, 0, 0);
      #pragma unroll
      for (int nt = 0; nt < 4; ++nt) {
        int vrow = nt*16 + qq;
        int vcol = (c*32 + 8*g) ^ ((vrow & 7) << 3);
        f16x8 vb = *(const f16x8*)&Vl[cur][vrow*64 + vcol];
        accO[nt] = __builtin_amdgcn_mfma_f32_16x16x32_f16(pa, vb, accO[nt], 0, 0, 0);
      }
    }
    __builtin_amdgcn_s_setprio(0);
  }

  // epilogue: y[b][t][h*64+d] = O / l, f16 (l already in accO's layout)
  #pragma unroll
  for (int r = 0; r < 4; ++r) {
    float invr = 1.0f / accS[r];
    int t = qs + wid*16 + g*4 + r;
    #pragma unroll
    for (int nt = 0; nt < 4; ++nt) {
      int d = nt*16 + qq;
      y[((size_t)(b*NT + t))*NC + h*ND + d] = f2h(accO[nt][r] * invr);
    }
  }
}

// ---------------- launch ----------------
extern "C" void kernel_launch(void* const* d_in, const int* in_sizes, int n_in,
                              void* d_out, int out_size, void* d_ws, size_t ws_size,
                              hipStream_t stream) {
  const float* x  = (const float*)d_in[0];
  const float* Wq = (const float*)d_in[1];
  const float* Wk = (const float*)d_in[2];
  const float* Wv = (const float*)d_in[3];
  const float* Wp = (const float*)d_in[4];

  u16* xb   = (u16*)d_ws;                       // [4096][1024]
  u16* wqkv = xb   + (size_t)NM*NC;             // [3072][1024] (Wq|Wk|Wv rows)
  u16* wpj  = wqkv + (size_t)3*NC*NC;           // [1024][1024] (contiguous after wqkv)
  u16* qb   = wpj  + (size_t)NC*NC;             // [BH][T][D], pre-scaled log2e/8
  u16* kb   = qb   + (size_t)NM*NC;             // [BH][T][D]
  u16* vtb  = kb   + (size_t)NM*NC;             // [BH][D][T]
  u16* yb   = vtb  + (size_t)NM*NC;             // [4096][1024]
  size_t need = ((size_t)NM*NC*5 + (size_t)4*NC*NC) * sizeof(u16);
  if (ws_size < need) return;                   // fail loudly (output stays zero)

  cvt_kernel<<<NM*NC/4/256, 256, 0, stream>>>(x, xb, NM*NC/4);
  cvtw_kernel<<<4*NC*NC/4/256, 256, 0, stream>>>(Wq, Wk, Wv, Wp, wqkv);

  gemm_bt<0><<<dim3(3*NC/128, NM/128), 256, 0, stream>>>(xb, wqkv, NC, 3*NC,
                                                         qb, kb, vtb, nullptr);
  attn_kernel<<<dim3(NB*NH, 32), 256, 0, stream>>>(qb, kb, vtb, yb);
  gemm_bt<1><<<dim3(NC/128, NM/128), 256, 0, stream>>>(yb, wpj, NC, NC,
                                                       nullptr, nullptr, nullptr,
                                                       (float*)d_out);
}

// Round 10
// 113.013 us; speedup vs baseline: 1.4037x; 1.0247x over previous
//
#include <hip/hip_runtime.h>
#include <stdint.h>

typedef uint16_t u16;
typedef uint32_t u32;
typedef __attribute__((ext_vector_type(8))) _Float16 f16x8;
typedef __attribute__((ext_vector_type(4))) float f32x4;
typedef __attribute__((ext_vector_type(2))) uint32_t u32x2;

#define NB 2
#define NT 2048
#define NC 1024
#define NH 16
#define ND 64
#define NM (NB*NT)   // 4096 rows of x
#define LOG2E 1.44269504088896340736f
#define PSTRIDE 4608   // u16 elems per partial slot: 64*64 O + 64 m(f32) + 64 l(f32) + pad

__device__ __forceinline__ u16 f2h(float f) {
  _Float16 h = (_Float16)f;   // RNE
  return __builtin_bit_cast(u16, h);
}

// ---------------- f32 -> f16 convert, 4 elems/thread ----------------
__global__ __launch_bounds__(256) void cvt_kernel(const float* __restrict__ src,
                                                  u16* __restrict__ dst, int n4) {
  int i = blockIdx.x * 256 + threadIdx.x;
  if (i >= n4) return;
  float4 v = ((const float4*)src)[i];
  ushort4 o;
  o.x = f2h(v.x); o.y = f2h(v.y); o.z = f2h(v.z); o.w = f2h(v.w);
  ((ushort4*)dst)[i] = o;
}

// 4 weights -> one contiguous f16 region (Wq|Wk|Wv|Wproj)
__global__ __launch_bounds__(256) void cvtw_kernel(const float* __restrict__ w0,
                                                   const float* __restrict__ w1,
                                                   const float* __restrict__ w2,
                                                   const float* __restrict__ w3,
                                                   u16* __restrict__ dst) {
  int i = blockIdx.x * 256 + threadIdx.x;       // 0 .. 4*NC*NC/4
  int which = i >> 18;                          // NC*NC/4 = 262144
  const float* src = (which == 0) ? w0 : (which == 1) ? w1 : (which == 2) ? w2 : w3;
  int j = i & 262143;
  float4 v = ((const float4*)src)[j];
  ushort4 o;
  o.x = f2h(v.x); o.y = f2h(v.y); o.z = f2h(v.z); o.w = f2h(v.w);
  ((ushort4*)dst)[i] = o;
}

// ---------------- async global->LDS 16B ----------------
__device__ __forceinline__ void gload16(const void* g, void* l) {
  __builtin_amdgcn_global_load_lds(
      (const __attribute__((address_space(1))) void*)g,
      (__attribute__((address_space(3))) void*)l, 16, 0, 0);
}

// ---------------- GEMM, both operands k-major (C[m][n] = sum_k A[m][k]*B[n][k]) ---
// Double-buffered staging + XOR-swizzled LDS (conflict-free ds_read_b128).
// EPI 0: QKV epilogue, LDS re-tiled + coalesced 16B stores.
// EPI 1: f32 row-major output.
template<int EPI>
__global__ __launch_bounds__(256) void gemm_bt(const u16* __restrict__ A,
                                               const u16* __restrict__ Bw,
                                               int K, int N,
                                               u16* __restrict__ oq, u16* __restrict__ okk,
                                               u16* __restrict__ ovt,
                                               float* __restrict__ of) {
  __shared__ __align__(16) u16 SH[4*128*64];   // 64 KB: A dbuf | B dbuf
  u16* Al = SH;
  u16* Bl = SH + 2*128*64;
  const int tid = threadIdx.x, lane = tid & 63, wid = tid >> 6;
  const int g = lane >> 4, qq = lane & 15;
  const int wm = wid >> 1, wn = wid & 1;
  const int m0 = blockIdx.y * 128, n0 = blockIdx.x * 128;
  const int srow = lane >> 3;            // row within an 8-row staging issue
  const int scol8 = (lane & 7) ^ srow;   // pre-swizzled 16B-slot in global source

  f32x4 acc[4][4] = {};
  const int nk = K >> 6;

  #pragma unroll
  for (int pp = 0; pp < 4; ++pp) {
    int r = wid*32 + pp*8;
    gload16(A  + (size_t)(m0 + r + srow)*K + scol8*8, &Al[r*64]);
    gload16(Bw + (size_t)(n0 + r + srow)*K + scol8*8, &Bl[r*64]);
  }

  for (int kt = 0; kt < nk; ++kt) {
    const int cur = kt & 1;
    __syncthreads();
    if (kt + 1 < nk) {
      const int k1 = (kt + 1) << 6;
      #pragma unroll
      for (int pp = 0; pp < 4; ++pp) {
        int r = wid*32 + pp*8;
        gload16(A  + (size_t)(m0 + r + srow)*K + k1 + scol8*8, &Al[(cur^1)*8192 + r*64]);
        gload16(Bw + (size_t)(n0 + r + srow)*K + k1 + scol8*8, &Bl[(cur^1)*8192 + r*64]);
      }
    }
    #pragma unroll
    for (int kk = 0; kk < 2; ++kk) {
      f16x8 af[4], bfr[4];
      #pragma unroll
      for (int mt = 0; mt < 4; ++mt) {
        int row = wm*64 + mt*16 + qq;
        af[mt] = *(const f16x8*)&Al[cur*8192 + row*64 + (((kk*4 + g) ^ (qq & 7))*8)];
      }
      #pragma unroll
      for (int nt = 0; nt < 4; ++nt) {
        int row = wn*64 + nt*16 + qq;
        bfr[nt] = *(const f16x8*)&Bl[cur*8192 + row*64 + (((kk*4 + g) ^ (qq & 7))*8)];
      }
      #pragma unroll
      for (int mt = 0; mt < 4; ++mt)
        #pragma unroll
        for (int nt = 0; nt < 4; ++nt)
          acc[mt][nt] = __builtin_amdgcn_mfma_f32_16x16x32_f16(af[mt], bfr[nt], acc[mt][nt], 0, 0, 0);
    }
  }

  if (EPI == 0) {
    __syncthreads();
    u16* reg = SH + wid*4096;
    const int sel = n0 >> 10;
    const int h = ((n0 & 1023) >> 6) + wn;
    const int bq = m0 >> 11;

    if (sel < 2) {
      const float scale = (sel == 0) ? 0.125f*LOG2E : 1.0f;
      #pragma unroll
      for (int mt = 0; mt < 4; ++mt)
        #pragma unroll
        for (int r = 0; r < 4; ++r) {
          int mloc = mt*16 + g*4 + r;
          #pragma unroll
          for (int nt = 0; nt < 4; ++nt) {
            int d = nt*16 + qq;
            reg[mloc*64 + (d ^ (g << 4))] = f2h(acc[mt][nt][r] * scale);
          }
        }
      u16* dst = (sel == 0) ? oq : okk;
      const int slot = lane & 7;
      #pragma unroll
      for (int i = 0; i < 8; ++i) {
        int row = i*8 + (lane >> 3);
        int physslot = slot ^ (((row >> 2) & 3) << 1);
        f16x8 vvv = *(const f16x8*)&reg[row*64 + physslot*8];
        int m = m0 + wm*64 + row;
        int t = m & (NT-1);
        *(f16x8*)(dst + (((size_t)(bq*NH + h)*NT + t)*ND) + slot*8) = vvv;
      }
    } else {
      #pragma unroll
      for (int nt = 0; nt < 4; ++nt) {
        int d = nt*16 + qq;
        int f = (d & 7) << 3;
        #pragma unroll
        for (int mt = 0; mt < 4; ++mt)
          #pragma unroll
          for (int rp = 0; rp < 2; ++rp) {
            int r = rp*2;
            int mloc = mt*16 + g*4 + r;
            u32 pk = (u32)f2h(acc[mt][nt][r]) | ((u32)f2h(acc[mt][nt][r+1]) << 16);
            *(u32*)&reg[d*64 + (mloc ^ f)] = pk;
          }
      }
      const int slot = lane & 7;
      const int t0 = m0 + wm*64;
      #pragma unroll
      for (int i = 0; i < 8; ++i) {
        int d = i*8 + (lane >> 3);
        int physslot = slot ^ (d & 7);
        f16x8 vvv = *(const f16x8*)&reg[d*64 + physslot*8];
        int t = (t0 & (NT-1)) + slot*8;
        *(f16x8*)(ovt + ((size_t)(bq*NH + h)*ND + d)*NT + t) = vvv;
      }
    }
  } else {
    #pragma unroll
    for (int mt = 0; mt < 4; ++mt)
      #pragma unroll
      for (int r = 0; r < 4; ++r) {
        int m = m0 + wm*64 + mt*16 + g*4 + r;
        #pragma unroll
        for (int nt = 0; nt < 4; ++nt) {
          int n = n0 + wn*64 + nt*16 + qq;
          of[(size_t)m*N + n] = acc[mt][nt][r];
        }
      }
  }
}

// ---------------- flash attention: split-kv work items, greedy-LPT dispatch ---
// Work item = (qtile, kstart, kcount, mode). qtiles 0..15: single item (direct y).
// qtiles 16..31: two kv-halves (mode 1/2) writing normalized partials
// (O/l f16 [64][64], m f32[64], l f32[64]) to ws; combine_kernel merges.
// grid (x=bh 32, y=48 items, DESCENDING size) -> linear id = bh + 32y:
//   XCD = id%8 = bh%8 (K/V L2-resident); dispatch order = biggest items first
//   -> hardware slot-refill approximates LPT; chain max halves (32->16 iters).
#define IT(q,s,c,m) ((u32)(q) | ((u32)(s)<<8) | ((u32)(c)<<16) | ((u32)(m)<<24))
__global__ __launch_bounds__(256) void attn_kernel(const u16* __restrict__ q,
                                                   const u16* __restrict__ k,
                                                   const u16* __restrict__ vt,
                                                   u16* __restrict__ y,
                                                   u16* __restrict__ part) {
  static const u32 items[48] = {
    IT(15,0,16,0), IT(30,0,16,1), IT(31,0,16,1), IT(31,16,16,2),
    IT(14,0,15,0), IT(28,0,15,1), IT(29,0,15,1), IT(29,15,15,2), IT(30,16,15,2),
    IT(13,0,14,0), IT(26,0,14,1), IT(27,0,14,1), IT(27,14,14,2), IT(28,15,14,2),
    IT(12,0,13,0), IT(24,0,13,1), IT(25,0,13,1), IT(25,13,13,2), IT(26,14,13,2),
    IT(11,0,12,0), IT(22,0,12,1), IT(23,0,12,1), IT(23,12,12,2), IT(24,13,12,2),
    IT(10,0,11,0), IT(20,0,11,1), IT(21,0,11,1), IT(21,11,11,2), IT(22,12,11,2),
    IT( 9,0,10,0), IT(18,0,10,1), IT(19,0,10,1), IT(19,10,10,2), IT(20,11,10,2),
    IT( 8,0, 9,0), IT(16,0, 9,1), IT(17,0, 9,1), IT(17, 9, 9,2), IT(18,10, 9,2),
    IT( 7,0, 8,0), IT(16,9, 8,2),
    IT( 6,0, 7,0), IT( 5,0, 6,0), IT( 4,0, 5,0), IT( 3,0, 4,0),
    IT( 2,0, 3,0), IT( 1,0, 2,0), IT( 0,0, 1,0)
  };
  __shared__ __align__(16) u16 Kl[2][64*64];
  __shared__ __align__(16) u16 Vl[2][64*64];
  __shared__ __align__(16) u16 Pl[4*16*64];
  const int tid = threadIdx.x, lane = tid & 63, wid = tid >> 6;
  const int g = lane >> 4, qq = lane & 15;
  const int bh = blockIdx.x;
  const u32 it = items[blockIdx.y];
  const int qtile = it & 255;
  const int ks = (it >> 8) & 255;
  const int kc = (it >> 16) & 255;
  const int mode = it >> 24;
  const int qs = qtile * 64;
  const u16* qp = q  + (size_t)bh*NT*ND;
  const u16* kp = k  + (size_t)bh*NT*ND;
  const u16* vp = vt + (size_t)bh*ND*NT;
  const int b = bh >> 4, h = bh & 15;
  const int srow = lane >> 3;
  const int scol8 = (lane & 7) ^ (srow & 7);  // pre-swizzled 16B-slot in global source
  u16* pl = &Pl[wid*1024];
  u32* plw = (u32*)pl;

  // Q B-fragment in registers (col q = qs + wid*16 + qq)
  f16x8 aq[2];
  {
    int t = qs + wid*16 + qq;
    #pragma unroll
    for (int c = 0; c < 2; ++c)
      aq[c] = *(const f16x8*)(qp + (size_t)t*ND + c*32 + 8*g);
  }

  f16x8 vones;
  #pragma unroll
  for (int i = 0; i < 8; ++i) vones[i] = (_Float16)1.0f;

  f32x4 accO[4] = {};               // O[q-local = g*4+r][d = nt*16+qq]
  f32x4 accS = {};                  // row-sum l[q-local = g*4+r] (ones-MFMA)
  float m_run = -1e30f;             // per-lane, row q = qq (replicated across g)

  // prologue: stage kv tile ks into buf 0
  #pragma unroll
  for (int pp = 0; pp < 2; ++pp) {
    int issue = wid*2 + pp;
    int row = issue*8 + srow;
    gload16(kp + (size_t)(ks*64 + row)*ND + scol8*8, &Kl[0][issue*512]);
    gload16(vp + (size_t)row*NT + ks*64 + scol8*8, &Vl[0][issue*512]);
  }

  for (int kt = ks; kt < ks + kc; ++kt) {
    const int kvs = kt*64;
    const int cur = (kt - ks) & 1;
    __syncthreads();                // stage(kt) drained; buf cur^1 free

    if (kt + 1 < ks + kc) {         // stage next tile under compute(kt)
      const int kvs2 = kvs + 64;
      #pragma unroll
      for (int pp = 0; pp < 2; ++pp) {
        int issue = wid*2 + pp;
        int row = issue*8 + srow;
        gload16(kp + (size_t)(kvs2 + row)*ND + scol8*8, &Kl[cur^1][issue*512]);
        gload16(vp + (size_t)row*NT + kvs2 + scol8*8, &Vl[cur^1][issue*512]);
      }
    }

    // S^T = K Q^T
    f32x4 sacc[4] = {};             // sacc[nt][r]: kv = kvs+nt*16+g*4+r, q = qs+wid*16+qq
    __builtin_amdgcn_s_setprio(1);
    #pragma unroll
    for (int c = 0; c < 2; ++c) {
      #pragma unroll
      for (int nt = 0; nt < 4; ++nt) {
        int row = nt*16 + qq;
        int col = (c*32 + 8*g) ^ ((row & 7) << 3);
        f16x8 kb = *(const f16x8*)&Kl[cur][row*64 + col];
        sacc[nt] = __builtin_amdgcn_mfma_f32_16x16x32_f16(kb, aq[c], sacc[nt], 0, 0, 0);
      }
    }
    __builtin_amdgcn_s_setprio(0);

    // causal mask (wave-uniform skip: only diagonal tiles mask)
    if (kvs + 63 > qs + wid*16) {
      int qg = qs + wid*16 + qq;
      #pragma unroll
      for (int nt = 0; nt < 4; ++nt)
        #pragma unroll
        for (int r = 0; r < 4; ++r)
          if (kvs + nt*16 + g*4 + r > qg) sacc[nt][r] = -1e30f;
    }

    // per-lane partial max (tree)
    float m0a = fmaxf(fmaxf(sacc[0][0], sacc[0][1]), fmaxf(sacc[0][2], sacc[0][3]));
    float m1a = fmaxf(fmaxf(sacc[1][0], sacc[1][1]), fmaxf(sacc[1][2], sacc[1][3]));
    float m2a = fmaxf(fmaxf(sacc[2][0], sacc[2][1]), fmaxf(sacc[2][2], sacc[2][3]));
    float m3a = fmaxf(fmaxf(sacc[3][0], sacc[3][1]), fmaxf(sacc[3][2], sacc[3][3]));
    float mloc = fmaxf(fmaxf(m0a, m1a), fmaxf(m2a, m3a));

    const bool defer = __all(mloc <= m_run + 8.f);   // P bounded by 2^8, f16-safe
    float mnew;
    if (defer) {
      mnew = m_run;
    } else {
      float mf = fmaxf(mloc, __shfl_xor(mloc, 16));
      mf = fmaxf(mf, __shfl_xor(mf, 32));
      mnew = fmaxf(m_run, mf);
      float a = exp2f(m_run - mnew);
      m_run = mnew;
      #pragma unroll
      for (int r = 0; r < 4; ++r) {
        float ar = __shfl(a, (lane & 48) + g*4 + r);
        #pragma unroll
        for (int nt = 0; nt < 4; ++nt) accO[nt][r] *= ar;
        accS[r] *= ar;
      }
    }

    // P = exp2(S - m); pack f16 pairs -> per-wave LDS [q][kv], b64 writes
    #pragma unroll
    for (int nt = 0; nt < 4; ++nt) {
      float p0 = exp2f(sacc[nt][0] - mnew);
      float p1 = exp2f(sacc[nt][1] - mnew);
      float p2 = exp2f(sacc[nt][2] - mnew);
      float p3 = exp2f(sacc[nt][3] - mnew);
      u32 pk0 = __builtin_bit_cast(u32, __builtin_amdgcn_cvt_pkrtz(p0, p1));
      u32 pk1 = __builtin_bit_cast(u32, __builtin_amdgcn_cvt_pkrtz(p2, p3));
      int kv0 = nt*16 + g*4;
      u32x2 pr; pr.x = pk0; pr.y = pk1;
      *(u32x2*)&plw[(qq*64 + (kv0 ^ ((qq & 7) << 3))) >> 1] = pr;
    }

    // O += P V ; l += P·1
    __builtin_amdgcn_s_setprio(1);
    #pragma unroll
    for (int c = 0; c < 2; ++c) {
      f16x8 pa = *(const f16x8*)&pl[qq*64 + ((c*32 + 8*g) ^ ((qq & 7) << 3))];
      accS = __builtin_amdgcn_mfma_f32_16x16x32_f16(pa, vones, accS, 0, 0, 0);
      #pragma unroll
      for (int nt = 0; nt < 4; ++nt) {
        int vrow = nt*16 + qq;
        int vcol = (c*32 + 8*g) ^ ((vrow & 7) << 3);
        f16x8 vb = *(const f16x8*)&Vl[cur][vrow*64 + vcol];
        accO[nt] = __builtin_amdgcn_mfma_f32_16x16x32_f16(pa, vb, accO[nt], 0, 0, 0);
      }
    }
    __builtin_amdgcn_s_setprio(0);
  }

  if (mode == 0) {
    // direct: y[b][t][h*64+d] = O / l
    #pragma unroll
    for (int r = 0; r < 4; ++r) {
      float invr = 1.0f / accS[r];
      int t = qs + wid*16 + g*4 + r;
      #pragma unroll
      for (int nt = 0; nt < 4; ++nt) {
        int d = nt*16 + qq;
        y[((size_t)(b*NT + t))*NC + h*ND + d] = f2h(accO[nt][r] * invr);
      }
    }
  } else {
    // partial: normalized O (f16), m, l (f32) to ws slot
    const int slot = ((bh << 4) + (qtile - 16))*2 + (mode - 1);
    u16* pp = part + (size_t)slot * PSTRIDE;
    float* hd = (float*)(pp + 4096);
    #pragma unroll
    for (int r = 0; r < 4; ++r) {
      int rloc = wid*16 + g*4 + r;
      float l = accS[r];
      float invr = 1.0f / l;
      float mr = __shfl(m_run, (lane & 48) + g*4 + r);
      #pragma unroll
      for (int nt = 0; nt < 4; ++nt) {
        int d = nt*16 + qq;
        pp[rloc*64 + d] = f2h(accO[nt][r] * invr);
      }
      if (qq == 0) { hd[rloc] = mr; hd[64 + rloc] = l; }
    }
  }
}

// ---------------- combine two kv-half partials -> y (qtiles 16..31) ----------
__global__ __launch_bounds__(256) void combine_kernel(const u16* __restrict__ part,
                                                      u16* __restrict__ y) {
  const int jj = blockIdx.x;              // qtile = 16 + jj
  const int bh = blockIdx.y;
  const int b = bh >> 4, h = bh & 15;
  const u16* p0 = part + (size_t)(((bh << 4) + jj)*2) * PSTRIDE;
  const u16* p1 = p0 + PSTRIDE;
  const float* h0 = (const float*)(p0 + 4096);
  const float* h1 = (const float*)(p1 + 4096);
  const int tid = threadIdx.x;
  const int d0 = (tid & 7) * 8;
  #pragma unroll
  for (int i = 0; i < 2; ++i) {
    int r = (tid >> 3) + 32*i;
    float m1 = h0[r], l1 = h0[64 + r];
    float m2 = h1[r], l2 = h1[64 + r];
    float mm = fmaxf(m1, m2);
    float w1 = exp2f(m1 - mm) * l1, w2 = exp2f(m2 - mm) * l2;
    float inv = 1.0f / (w1 + w2);
    float a1 = w1 * inv, a2 = w2 * inv;
    f16x8 o1 = *(const f16x8*)&p0[r*64 + d0];
    f16x8 o2 = *(const f16x8*)&p1[r*64 + d0];
    f16x8 out;
    #pragma unroll
    for (int e = 0; e < 8; ++e)
      out[e] = (_Float16)(a1 * (float)o1[e] + a2 * (float)o2[e]);
    int t = (16 + jj)*64 + r;
    *(f16x8*)(y + ((size_t)(b*NT + t))*NC + h*ND + d0) = out;
  }
}

// ---------------- launch ----------------
extern "C" void kernel_launch(void* const* d_in, const int* in_sizes, int n_in,
                              void* d_out, int out_size, void* d_ws, size_t ws_size,
                              hipStream_t stream) {
  const float* x  = (const float*)d_in[0];
  const float* Wq = (const float*)d_in[1];
  const float* Wk = (const float*)d_in[2];
  const float* Wv = (const float*)d_in[3];
  const float* Wp = (const float*)d_in[4];

  u16* xb   = (u16*)d_ws;                       // [4096][1024]; dead after gemm<0> -> partials
  u16* wqkv = xb   + (size_t)NM*NC;             // [3072][1024]; dead after gemm<0>
  u16* wpj  = wqkv + (size_t)3*NC*NC;           // [1024][1024] (needed by gemm<1>)
  u16* qb   = wpj  + (size_t)NC*NC;             // [BH][T][D], pre-scaled log2e/8
  u16* kb   = qb   + (size_t)NM*NC;             // [BH][T][D]
  u16* vtb  = kb   + (size_t)NM*NC;             // [BH][D][T]
  u16* yb   = vtb  + (size_t)NM*NC;             // [4096][1024]
  u16* part = xb;                               // 1024 slots x 9216B = 9.4MB (xb+wqkv = 14MB dead)
  size_t need = ((size_t)NM*NC*5 + (size_t)4*NC*NC) * sizeof(u16);
  if (ws_size < need) return;                   // fail loudly (output stays zero)

  cvt_kernel<<<NM*NC/4/256, 256, 0, stream>>>(x, xb, NM*NC/4);
  cvtw_kernel<<<4*NC*NC/4/256, 256, 0, stream>>>(Wq, Wk, Wv, Wp, wqkv);

  gemm_bt<0><<<dim3(3*NC/128, NM/128), 256, 0, stream>>>(xb, wqkv, NC, 3*NC,
                                                         qb, kb, vtb, nullptr);
  attn_kernel<<<dim3(NB*NH, 48), 256, 0, stream>>>(qb, kb, vtb, yb, part);
  combine_kernel<<<dim3(16, NB*NH), 256, 0, stream>>>(part, yb);
  gemm_bt<1><<<dim3(NC/128, NM/128), 256, 0, stream>>>(yb, wpj, NC, NC,
                                                       nullptr, nullptr, nullptr,
                                                       (float*)d_out);
}